// Round 1
// baseline (1136.491 us; speedup 1.0000x reference)
//
#include <hip/hip_runtime.h>
#include <math.h>

#define NN 10000
#define NE 160000
#define CC 32
#define TE 32

// ws layout (float offsets)
#define OFF_P1H 0
#define OFF_P3H 320000
#define OFF_P1N 1280000
#define OFF_P3N 1600000

// ---------------- node prep: p1h = tanh(p1@pp1_W+b), p3h = tanh(p3@pp3_W+b) ---
__global__ __launch_bounds__(256) void node_prep(
    const float* __restrict__ p1, const float* __restrict__ p3,
    const float* __restrict__ pp1_W, const float* __restrict__ pp1_b,
    const float* __restrict__ pp3_W, const float* __restrict__ pp3_b,
    float* __restrict__ p1h, float* __restrict__ p3h)
{
    __shared__ float Ws[2][CC * CC];
    __shared__ float bs[2][CC];
    int tid = threadIdx.x;
    for (int i = tid; i < CC * CC; i += 256) { Ws[0][i] = pp1_W[i]; Ws[1][i] = pp3_W[i]; }
    if (tid < CC) { bs[0][tid] = pp1_b[tid]; bs[1][tid] = pp3_b[tid]; }
    __syncthreads();
    int idx = blockIdx.x * 256 + tid;      // < NN*128
    int n = idx >> 7;
    int r = (idx >> 5) & 3;                // 0 -> p1, 1..3 -> p3 row d=r-1
    int c = idx & 31;
    int sel = (r == 0) ? 0 : 1;
    const float* in = (r == 0) ? (p1 + n * CC) : (p3 + (n * 3 + (r - 1)) * CC);
    float acc = bs[sel][c];
    #pragma unroll
    for (int k = 0; k < CC; ++k) acc += in[k] * Ws[sel][k * CC + c];
    float v = tanhf(acc);
    if (r == 0) p1h[n * CC + c] = v;
    else        p3h[(n * 3 + (r - 1)) * CC + c] = v;
}

// ---------------- fused edge kernel: TE=32 edges per 256-thread block --------
__global__ __launch_bounds__(256) void edge_kernel(
    const float* __restrict__ p1h, const float* __restrict__ p3h,
    const float* __restrict__ r3, const float* __restrict__ basis,
    const int* __restrict__ idx_i, const int* __restrict__ idx_j,
    const float* __restrict__ pi1_W1, const float* __restrict__ pi1_b1,
    const float* __restrict__ pi1_W2, const float* __restrict__ pi1_b2,
    const float* __restrict__ pi1_W3,
    const float* __restrict__ ii1_W, const float* __restrict__ ii1_b,
    const float* __restrict__ pi3_W1, const float* __restrict__ pi3_b1,
    const float* __restrict__ pi3_W2, const float* __restrict__ pi3_b2,
    const float* __restrict__ pi3_W3,
    const float* __restrict__ ii3_W, const float* __restrict__ ii3_b,
    float* __restrict__ p1n, float* __restrict__ p3n)
{
    __shared__ int   idxiL[TE];
    __shared__ int   idxjL[TE];
    __shared__ float basisL[TE][8];
    __shared__ float r3L[TE][3];
    __shared__ float i1L[TE][96];     // i1_1 | i1_2 | i1_3
    __shared__ float h2L[TE][96];     // pi1 h2; later reused as g2[e][d*32+c]
    __shared__ float wbuf[4224];      // staged small weights (phase-dependent)
    __shared__ float scratch[5568];   // inter/h1/g1 or swizzled W3 tile + i3pre
    // total LDS = 65408 B

    const int tid = threadIdx.x;
    const int eb = blockIdx.x * TE;

    // ---- phase 0: metadata + pi1_W1/b1 ----
    if (tid < TE) { idxiL[tid] = idx_i[eb + tid]; idxjL[tid] = idx_j[eb + tid]; }
    { int e = tid >> 3, b = tid & 7; basisL[e][b] = basis[(eb + e) * 8 + b]; }
    if (tid < TE * 3) { int e = tid / 3, d = tid - e * 3; r3L[e][d] = r3[(eb + e) * 3 + d]; }
    for (int i = tid; i < 64 * 32; i += 256) wbuf[i] = pi1_W1[i];
    if (tid < 32) wbuf[2048 + tid] = pi1_b1[tid];
    __syncthreads();

    // ---- stage inter1 = [p1h[i] | p1h[j]] -> scratch[0..2047] ----
    for (int t = tid; t < TE * 64; t += 256) {
        int e = t >> 6, k = t & 63;
        int node = (k < 32) ? idxiL[e] : idxjL[e];
        scratch[t] = p1h[node * CC + (k & 31)];
    }
    __syncthreads();

    // ---- phase 1: h1 = inter@W1+b1 -> scratch[2048 + e*32+c] ----
    for (int t = tid; t < TE * 32; t += 256) {
        int e = t >> 5, c = t & 31;
        float acc = wbuf[2048 + c];
        #pragma unroll 8
        for (int k = 0; k < 64; ++k) acc += scratch[e * 64 + k] * wbuf[k * 32 + c];
        scratch[2048 + t] = acc;
    }
    __syncthreads();
    for (int i = tid; i < 32 * 96; i += 256) wbuf[i] = pi1_W2[i];
    if (tid < 96) wbuf[3072 + tid] = pi1_b2[tid];
    __syncthreads();

    // ---- phase 2: h2 = h1@W2+b2 -> h2L[e][0..95] ----
    {
        int c0 = tid & 31, e0 = tid >> 5;
        float acc[3][4];
        for (int cj = 0; cj < 3; ++cj) {
            float bv = wbuf[3072 + c0 + 32 * cj];
            for (int ei = 0; ei < 4; ++ei) acc[cj][ei] = bv;
        }
        for (int k = 0; k < 32; ++k) {
            float h[4];
            #pragma unroll
            for (int ei = 0; ei < 4; ++ei) h[ei] = scratch[2048 + (e0 + 8 * ei) * 32 + k];
            #pragma unroll
            for (int cj = 0; cj < 3; ++cj) {
                float w = wbuf[k * 96 + c0 + 32 * cj];
                #pragma unroll
                for (int ei = 0; ei < 4; ++ei) acc[cj][ei] += h[ei] * w;
            }
        }
        for (int cj = 0; cj < 3; ++cj)
            for (int ei = 0; ei < 4; ++ei)
                h2L[e0 + 8 * ei][c0 + 32 * cj] = acc[cj][ei];
    }

    // ---- phase 3: i1[e][c] = sum_{k,b} h2[e][k]*W3[k][c*8+b]*basis[e][b] ----
    {
        const int eg = tid >> 5;     // 4-edge group
        const int cg = tid & 31;     // channel within pass
        for (int pass = 0; pass < 3; ++pass) {
            float acc[4][8];
            for (int i = 0; i < 4; ++i) for (int b = 0; b < 8; ++b) acc[i][b] = 0.f;
            for (int kt = 0; kt < 6; ++kt) {
                __syncthreads();
                for (int t = tid; t < 16 * 256; t += 256) {
                    int kl = t >> 8, cb = t & 255;
                    scratch[kl * 284 + cb + ((cb >> 5) << 2)] =
                        pi1_W3[(kt * 16 + kl) * 768 + pass * 256 + cb];
                }
                __syncthreads();
                for (int k = 0; k < 16; ++k) {
                    float h[4];
                    #pragma unroll
                    for (int i = 0; i < 4; ++i) h[i] = h2L[eg * 4 + i][kt * 16 + k];
                    const float4* wp = (const float4*)&scratch[k * 284 + cg * 8 + ((cg >> 2) << 2)];
                    float4 wa = wp[0], wb = wp[1];
                    #pragma unroll
                    for (int i = 0; i < 4; ++i) {
                        acc[i][0] += h[i] * wa.x; acc[i][1] += h[i] * wa.y;
                        acc[i][2] += h[i] * wa.z; acc[i][3] += h[i] * wa.w;
                        acc[i][4] += h[i] * wb.x; acc[i][5] += h[i] * wb.y;
                        acc[i][6] += h[i] * wb.z; acc[i][7] += h[i] * wb.w;
                    }
                }
            }
            for (int i = 0; i < 4; ++i) {
                int e = eg * 4 + i;
                float v = 0.f;
                #pragma unroll
                for (int b = 0; b < 8; ++b) v += acc[i][b] * basisL[e][b];
                i1L[e][pass * 32 + cg] = v;
            }
        }
    }
    __syncthreads();

    // ---- phase 4: i1a = tanh(i1_1@ii1_W+b) ; atomic into p1n[idx_j] ----
    for (int i = tid; i < 32 * 32; i += 256) wbuf[i] = ii1_W[i];
    if (tid < 32) wbuf[1024 + tid] = ii1_b[tid];
    __syncthreads();
    for (int t = tid; t < TE * 32; t += 256) {
        int e = t >> 5, c = t & 31;
        float acc = wbuf[1024 + c];
        #pragma unroll 8
        for (int k = 0; k < 32; ++k) acc += i1L[e][k] * wbuf[k * 32 + c];
        atomicAdd(&p1n[idxjL[e] * CC + c], tanhf(acc));
    }
    __syncthreads();

    // ---- phase 5: stage pi3 weights; per-d g2 -> h2L[e][d*32+c] ----
    for (int i = tid; i < 2048; i += 256) wbuf[i] = pi3_W1[i];
    for (int i = tid; i < 1024; i += 256) { wbuf[2080 + i] = pi3_W2[i]; wbuf[3136 + i] = ii3_W[i]; }
    if (tid < 32) { wbuf[2048 + tid] = pi3_b1[tid]; wbuf[3104 + tid] = pi3_b2[tid]; wbuf[4160 + tid] = ii3_b[tid]; }
    __syncthreads();

    for (int d = 0; d < 3; ++d) {
        for (int t = tid; t < TE * 64; t += 256) {
            int e = t >> 6, k = t & 63;
            int node = (k < 32) ? idxiL[e] : idxjL[e];
            scratch[t] = p3h[(node * 3 + d) * CC + (k & 31)];
        }
        __syncthreads();
        for (int t = tid; t < TE * 32; t += 256) {   // g1 = inter3@W1+b1
            int e = t >> 5, c = t & 31;
            float acc = wbuf[2048 + c];
            #pragma unroll 8
            for (int k = 0; k < 64; ++k) acc += scratch[e * 64 + k] * wbuf[k * 32 + c];
            scratch[2048 + t] = acc;
        }
        __syncthreads();
        for (int t = tid; t < TE * 32; t += 256) {   // g2 = g1@W2+b2
            int e = t >> 5, c = t & 31;
            float acc = wbuf[3104 + c];
            #pragma unroll 8
            for (int k = 0; k < 32; ++k) acc += scratch[2048 + e * 32 + k] * wbuf[2080 + k * 32 + c];
            h2L[e][d * 32 + c] = acc;
        }
        __syncthreads();
    }

    // ---- phase 6/7: per-d  i3pre = (g2@W3_3)·basis ; i3a=tanh(i3pre@ii3+b);
    //                 combine with i1_2,i1_3,r3 ; atomic into p3n[idx_j] ----
    {
        const int eg = tid >> 5;
        const int cg = tid & 31;
        for (int d = 0; d < 3; ++d) {
            float acc[4][8];
            for (int i = 0; i < 4; ++i) for (int b = 0; b < 8; ++b) acc[i][b] = 0.f;
            for (int kt = 0; kt < 2; ++kt) {
                __syncthreads();
                for (int t = tid; t < 16 * 256; t += 256) {
                    int kl = t >> 8, cb = t & 255;
                    scratch[kl * 284 + cb + ((cb >> 5) << 2)] =
                        pi3_W3[(kt * 16 + kl) * 256 + cb];
                }
                __syncthreads();
                for (int k = 0; k < 16; ++k) {
                    float h[4];
                    #pragma unroll
                    for (int i = 0; i < 4; ++i) h[i] = h2L[eg * 4 + i][d * 32 + kt * 16 + k];
                    const float4* wp = (const float4*)&scratch[k * 284 + cg * 8 + ((cg >> 2) << 2)];
                    float4 wa = wp[0], wb = wp[1];
                    #pragma unroll
                    for (int i = 0; i < 4; ++i) {
                        acc[i][0] += h[i] * wa.x; acc[i][1] += h[i] * wa.y;
                        acc[i][2] += h[i] * wa.z; acc[i][3] += h[i] * wa.w;
                        acc[i][4] += h[i] * wb.x; acc[i][5] += h[i] * wb.y;
                        acc[i][6] += h[i] * wb.z; acc[i][7] += h[i] * wb.w;
                    }
                }
            }
            for (int i = 0; i < 4; ++i) {             // fold basis -> i3pre
                int e = eg * 4 + i;
                float v = 0.f;
                #pragma unroll
                for (int b = 0; b < 8; ++b) v += acc[i][b] * basisL[e][b];
                scratch[4544 + e * 32 + cg] = v;
            }
            __syncthreads();
            for (int t = tid; t < TE * 32; t += 256) {
                int e = t >> 5, c = t & 31;
                float acc2 = wbuf[4160 + c];
                #pragma unroll 8
                for (int k = 0; k < 32; ++k) acc2 += scratch[4544 + e * 32 + k] * wbuf[3136 + k * 32 + c];
                float i3a = tanhf(acc2);
                float val = i3a * i1L[e][32 + c] + r3L[e][d] * i1L[e][64 + c];
                atomicAdd(&p3n[(idxjL[e] * 3 + d) * CC + c], val);
            }
        }
    }
}

// ---------------- finalize: p1o = sum_d p3n^2 + p1n ; p3o = p3n * p1o --------
__global__ __launch_bounds__(256) void finalize_kernel(
    const float* __restrict__ p1n, const float* __restrict__ p3n,
    float* __restrict__ out)
{
    int t = blockIdx.x * 256 + threadIdx.x;   // < NN*32
    int n = t >> 5, c = t & 31;
    float a0 = p3n[(n * 3 + 0) * CC + c];
    float a1 = p3n[(n * 3 + 1) * CC + c];
    float a2 = p3n[(n * 3 + 2) * CC + c];
    float p1o = p1n[t] + a0 * a0 + a1 * a1 + a2 * a2;
    out[t] = p1o;
    float* o3 = out + NN * CC;
    o3[(n * 3 + 0) * CC + c] = a0 * p1o;
    o3[(n * 3 + 1) * CC + c] = a1 * p1o;
    o3[(n * 3 + 2) * CC + c] = a2 * p1o;
}

extern "C" void kernel_launch(void* const* d_in, const int* in_sizes, int n_in,
                              void* d_out, int out_size, void* d_ws, size_t ws_size,
                              hipStream_t stream) {
    const float* p1     = (const float*)d_in[0];
    const float* p3     = (const float*)d_in[1];
    const float* r3     = (const float*)d_in[2];
    const float* basis  = (const float*)d_in[3];
    const int*   idx_i  = (const int*)d_in[4];
    const int*   idx_j  = (const int*)d_in[5];
    const float* pp1_W  = (const float*)d_in[6];
    const float* pp1_b  = (const float*)d_in[7];
    const float* pi1_W1 = (const float*)d_in[8];
    const float* pi1_b1 = (const float*)d_in[9];
    const float* pi1_W2 = (const float*)d_in[10];
    const float* pi1_b2 = (const float*)d_in[11];
    const float* pi1_W3 = (const float*)d_in[12];
    const float* ii1_W  = (const float*)d_in[13];
    const float* ii1_b  = (const float*)d_in[14];
    const float* pp3_W  = (const float*)d_in[15];
    const float* pp3_b  = (const float*)d_in[16];
    const float* pi3_W1 = (const float*)d_in[17];
    const float* pi3_b1 = (const float*)d_in[18];
    const float* pi3_W2 = (const float*)d_in[19];
    const float* pi3_b2 = (const float*)d_in[20];
    const float* pi3_W3 = (const float*)d_in[21];
    const float* ii3_W  = (const float*)d_in[22];
    const float* ii3_b  = (const float*)d_in[23];

    float* ws  = (float*)d_ws;
    float* p1h = ws + OFF_P1H;
    float* p3h = ws + OFF_P3H;
    float* p1n = ws + OFF_P1N;
    float* p3n = ws + OFF_P3N;

    hipMemsetAsync(p1n, 0, (size_t)(320000 + 960000) * sizeof(float), stream);

    node_prep<<<dim3(5000), dim3(256), 0, stream>>>(p1, p3, pp1_W, pp1_b, pp3_W, pp3_b, p1h, p3h);

    edge_kernel<<<dim3(NE / TE), dim3(256), 0, stream>>>(
        p1h, p3h, r3, basis, idx_i, idx_j,
        pi1_W1, pi1_b1, pi1_W2, pi1_b2, pi1_W3, ii1_W, ii1_b,
        pi3_W1, pi3_b1, pi3_W2, pi3_b2, pi3_W3, ii3_W, ii3_b,
        p1n, p3n);

    finalize_kernel<<<dim3(1250), dim3(256), 0, stream>>>(p1n, p3n, (float*)d_out);
}

// Round 2
// 241.033 us; speedup vs baseline: 4.7151x; 4.7151x over previous
//
#include <hip/hip_runtime.h>
#include <math.h>

#define NN 10000
#define NE 160000
#define TE 64

typedef __attribute__((ext_vector_type(8))) short s8v;
typedef __attribute__((ext_vector_type(4))) float f4v;
typedef unsigned short u16;

// ---- ws byte layout ----
#define OFF_P1HB 0u          // N*32 bf16      = 640000 B
#define OFF_P3HB 640000u     // N*3*32 bf16    = 1920000 B
#define OFF_P1N  2560000u    // N*32 f32       = 1280000 B
#define OFF_P3N  3840000u    // N*3*32 f32     = 3840000 B
#define OFF_WB   7680000u    // 103936 bf16 weights

// ---- wb (ushort element) offsets ----
#define OW1T1 0       // [32][72]
#define OW2T1 2304    // [96][40]
#define OII1T 6144    // [32][40]
#define OW1T3 7424    // [32][72]
#define OW2T3 9728    // [32][40]
#define OII3T 11008   // [32][40]
#define OBLG  12288   // [12][96][72]
#define OBL3G 95232   // [2][32][136]
#define NWB   103936

__device__ __forceinline__ short f2b(float f) {
    unsigned u = __float_as_uint(f);
    u += 0x7fffu + ((u >> 16) & 1u);
    return (short)(u >> 16);
}
__device__ __forceinline__ float b2f(u16 s) {
    return __uint_as_float(((unsigned)s) << 16);
}

// ---------------- node prep: p1h/p3h = tanh(x@W+b) -> bf16 ----------------
__global__ __launch_bounds__(256) void node_prep(
    const float* __restrict__ p1, const float* __restrict__ p3,
    const float* __restrict__ pp1_W, const float* __restrict__ pp1_b,
    const float* __restrict__ pp3_W, const float* __restrict__ pp3_b,
    u16* __restrict__ p1hb, u16* __restrict__ p3hb)
{
    __shared__ float Ws[2][32 * 32];
    __shared__ float bsm[2][32];
    int tid = threadIdx.x;
    for (int i = tid; i < 32 * 32; i += 256) { Ws[0][i] = pp1_W[i]; Ws[1][i] = pp3_W[i]; }
    if (tid < 32) { bsm[0][tid] = pp1_b[tid]; bsm[1][tid] = pp3_b[tid]; }
    __syncthreads();
    int idx = blockIdx.x * 256 + tid;      // < NN*128
    int n = idx >> 7;
    int r = (idx >> 5) & 3;
    int c = idx & 31;
    int sel = (r == 0) ? 0 : 1;
    const float* in = (r == 0) ? (p1 + n * 32) : (p3 + (n * 3 + (r - 1)) * 32);
    float acc = bsm[sel][c];
    #pragma unroll
    for (int k = 0; k < 32; ++k) acc += in[k] * Ws[sel][k * 32 + c];
    short v = f2b(tanhf(acc));
    if (r == 0) p1hb[n * 32 + c] = (u16)v;
    else        p3hb[(n * 3 + (r - 1)) * 32 + c] = (u16)v;
}

// ---------------- weight prep: transpose/convert to bf16 with pads --------
__global__ __launch_bounds__(256) void wprep(
    const float* __restrict__ W1, const float* __restrict__ W2,
    const float* __restrict__ W3, const float* __restrict__ ii1,
    const float* __restrict__ W13, const float* __restrict__ W23,
    const float* __restrict__ W33, const float* __restrict__ ii3,
    u16* __restrict__ wb)
{
    int i0 = blockIdx.x * 256 + threadIdx.x;
    if (i0 >= NWB) return;
    int i = i0;
    float v = 0.f;
    if (i < 2304) { int c = i / 72, k = i % 72; if (k < 64) v = W1[k * 32 + c]; }
    else if ((i -= 2304) < 3840) { int c = i / 40, k = i % 40; if (k < 32) v = W2[k * 96 + c]; }
    else if ((i -= 3840) < 1280) { int c = i / 40, k = i % 40; if (k < 32) v = ii1[k * 32 + c]; }
    else if ((i -= 1280) < 2304) { int c = i / 72, k = i % 72; if (k < 64) v = W13[k * 32 + c]; }
    else if ((i -= 2304) < 1280) { int c = i / 40, k = i % 40; if (k < 32) v = W23[k * 32 + c]; }
    else if ((i -= 1280) < 1280) { int c = i / 40, k = i % 40; if (k < 32) v = ii3[k * 32 + c]; }
    else if ((i -= 1280) < 82944) {
        int ch = i / 6912, rem = i % 6912, c = rem / 72, kbl = rem % 72;
        if (kbl < 64) { int kb = ch * 64 + kbl; v = W3[(kb >> 3) * 768 + c * 8 + (kb & 7)]; }
    } else {
        i -= 82944;
        int ch = i / 4352, rem = i % 4352, c = rem / 136, kbl = rem % 136;
        if (kbl < 128) { int kb = ch * 128 + kbl; v = W33[(kb >> 3) * 256 + c * 8 + (kb & 7)]; }
    }
    wb[i0] = (u16)f2b(v);
}

// ---------------- fused edge kernel: TE=64 edges, 4 waves, all-MFMA -------
__global__ __launch_bounds__(256) void edge_kernel(
    const u16* __restrict__ p1hb, const u16* __restrict__ p3hb,
    const float* __restrict__ r3, const float* __restrict__ basis,
    const int* __restrict__ idx_i, const int* __restrict__ idx_j,
    const u16* __restrict__ wb,
    const float* __restrict__ b1, const float* __restrict__ b2,
    const float* __restrict__ ii1b,
    const float* __restrict__ b13, const float* __restrict__ b23,
    const float* __restrict__ ii3b,
    float* __restrict__ p1n, float* __restrict__ p3n)
{
    // LDS map (bytes): see analysis; total 50688
    __shared__ int4 smem4[50688 / 16];
    char* sm = (char*)smem4;
    int*   sIdxI = (int*)(sm + 0);
    int*   sIdxJ = (int*)(sm + 256);
    float* sBas  = (float*)(sm + 512);      // [64][8]
    float* sR3   = (float*)(sm + 2560);     // [64][4]
    u16*   sA    = (u16*)(sm + 3584);       // regionA 13824B: interb[64][72] | Bl[96][72] | Bl3[32][136]
    u16*   sH2   = (u16*)(sm + 17408);      // [64][104] ; pi3: g2b [64][40]
    u16*   sBufA = (u16*)(sm + 30720);      // [64][40]
    u16*   sW1t  = (u16*)(sm + 35840);      // [32][72]
    u16*   sW2t  = (u16*)(sm + 40448);      // [96][40]
    u16*   sIIt  = (u16*)(sm + 48128);      // [32][40]

    const int tid = threadIdx.x;
    const int w   = tid >> 6;
    const int l   = tid & 63;
    const int r16 = l & 15;
    const int kg  = l >> 4;
    const int eb  = blockIdx.x * TE;

    // ---- stage meta + pi1 small weights ----
    if (tid < 64) { sIdxI[tid] = idx_i[eb + tid]; sIdxJ[tid] = idx_j[eb + tid]; }
    if (tid < 128) {
        int e = tid >> 1;
        ((float4*)(sBas + e * 8))[tid & 1] = ((const float4*)(basis + (size_t)(eb + e) * 8))[tid & 1];
    }
    if (tid >= 128 && tid < 192) {
        int e = tid - 128;
        sR3[e * 4 + 0] = r3[(eb + e) * 3 + 0];
        sR3[e * 4 + 1] = r3[(eb + e) * 3 + 1];
        sR3[e * 4 + 2] = r3[(eb + e) * 3 + 2];
    }
    {
        const int4* g1w = (const int4*)((const char*)wb + OW1T1 * 2);
        const int4* g2w = (const int4*)((const char*)wb + OW2T1 * 2);
        const int4* giw = (const int4*)((const char*)wb + OII1T * 2);
        for (int i = tid; i < 288; i += 256) ((int4*)sW1t)[i] = g1w[i];
        for (int i = tid; i < 480; i += 256) ((int4*)sW2t)[i] = g2w[i];
        for (int i = tid; i < 160; i += 256) ((int4*)sIIt)[i] = giw[i];
    }
    __syncthreads();

    // ---- gather inter1 = [p1h[i] | p1h[j]] bf16 -> sA [64][72] ----
    for (int i = tid; i < 512; i += 256) {
        int e = i >> 3, hf = (i >> 2) & 1, q = i & 3;
        int node = hf ? sIdxJ[e] : sIdxI[e];
        *(int4*)(sA + e * 72 + hf * 32 + q * 8) = *(const int4*)(p1hb + (size_t)node * 32 + q * 8);
    }
    __syncthreads();

    // ---- h1 = inter1@W1 + b1 -> bufA bf16 [64][40] ----
    {
        f4v acc0 = {0.f, 0.f, 0.f, 0.f}, acc1 = {0.f, 0.f, 0.f, 0.f};
        #pragma unroll
        for (int ks = 0; ks < 2; ++ks) {
            s8v av = *(const s8v*)(sA + (16 * w + r16) * 72 + 32 * ks + 8 * kg);
            s8v b0 = *(const s8v*)(sW1t + (r16) * 72 + 32 * ks + 8 * kg);
            s8v b1f = *(const s8v*)(sW1t + (16 + r16) * 72 + 32 * ks + 8 * kg);
            acc0 = __builtin_amdgcn_mfma_f32_16x16x32_bf16(av, b0, acc0, 0, 0, 0);
            acc1 = __builtin_amdgcn_mfma_f32_16x16x32_bf16(av, b1f, acc1, 0, 0, 0);
        }
        float bb0 = b1[r16], bb1 = b1[16 + r16];
        #pragma unroll
        for (int rr = 0; rr < 4; ++rr) {
            sBufA[(16 * w + 4 * kg + rr) * 40 + r16]      = (u16)f2b(acc0[rr] + bb0);
            sBufA[(16 * w + 4 * kg + rr) * 40 + 16 + r16] = (u16)f2b(acc1[rr] + bb1);
        }
    }
    __syncthreads();

    // ---- h2 = h1@W2 + b2 -> sH2 bf16 [64][104] ----
    {
        s8v av = *(const s8v*)(sBufA + (16 * w + r16) * 40 + 8 * kg);
        #pragma unroll
        for (int nt = 0; nt < 6; ++nt) {
            f4v acc = {0.f, 0.f, 0.f, 0.f};
            s8v bv = *(const s8v*)(sW2t + (16 * nt + r16) * 40 + 8 * kg);
            acc = __builtin_amdgcn_mfma_f32_16x16x32_bf16(av, bv, acc, 0, 0, 0);
            float bb = b2[16 * nt + r16];
            #pragma unroll
            for (int rr = 0; rr < 4; ++rr)
                sH2[(16 * w + 4 * kg + rr) * 104 + 16 * nt + r16] = (u16)f2b(acc[rr] + bb);
        }
    }

    // ---- W3-pi1 (u-form): i1[e][c] = sum_kb (h2*basis) * Bl[c][kb] ----
    float bs[8];
    #pragma unroll
    for (int j = 0; j < 8; ++j) bs[j] = sBas[(16 * w + r16) * 8 + j];

    f4v acc[6];
    #pragma unroll
    for (int nt = 0; nt < 6; ++nt) { f4v z = {0.f, 0.f, 0.f, 0.f}; acc[nt] = z; }

    {
        const int4* gBl = (const int4*)((const char*)wb + OBLG * 2);
        int4 pre[4];
        #pragma unroll
        for (int j2 = 0; j2 < 4; ++j2) { int s = tid + 256 * j2; if (s < 864) pre[j2] = gBl[s]; }
        for (int ch = 0; ch < 12; ++ch) {
            __syncthreads();
            #pragma unroll
            for (int j2 = 0; j2 < 4; ++j2) { int s = tid + 256 * j2; if (s < 864) ((int4*)sA)[s] = pre[j2]; }
            if (ch + 1 < 12) {
                #pragma unroll
                for (int j2 = 0; j2 < 4; ++j2) { int s = tid + 256 * j2; if (s < 864) pre[j2] = gBl[(ch + 1) * 864 + s]; }
            }
            __syncthreads();
            #pragma unroll
            for (int t = 0; t < 2; ++t) {
                float h = b2f(sH2[(16 * w + r16) * 104 + 8 * ch + 4 * t + kg]);
                s8v av;
                #pragma unroll
                for (int j = 0; j < 8; ++j) av[j] = f2b(h * bs[j]);
                #pragma unroll
                for (int nt = 0; nt < 6; ++nt) {
                    s8v bv = *(const s8v*)(sA + (16 * nt + r16) * 72 + 32 * t + 8 * kg);
                    acc[nt] = __builtin_amdgcn_mfma_f32_16x16x32_bf16(av, bv, acc[nt], 0, 0, 0);
                }
            }
        }
    }
    // i1_1 -> bufA bf16 ; keep i1_2/i1_3 in registers
    #pragma unroll
    for (int nt = 0; nt < 2; ++nt)
        #pragma unroll
        for (int rr = 0; rr < 4; ++rr)
            sBufA[(16 * w + 4 * kg + rr) * 40 + 16 * nt + r16] = (u16)f2b(acc[nt][rr]);
    f4v i12a = acc[2], i12b = acc[3], i13a = acc[4], i13b = acc[5];
    __syncthreads();

    // ---- ii1: tanh(i1_1@ii1_W + b) -> atomic p1n[idx_j] ----
    {
        s8v av = *(const s8v*)(sBufA + (16 * w + r16) * 40 + 8 * kg);
        #pragma unroll
        for (int nt = 0; nt < 2; ++nt) {
            f4v ia = {0.f, 0.f, 0.f, 0.f};
            s8v bv = *(const s8v*)(sIIt + (16 * nt + r16) * 40 + 8 * kg);
            ia = __builtin_amdgcn_mfma_f32_16x16x32_bf16(av, bv, ia, 0, 0, 0);
            float bb = ii1b[16 * nt + r16];
            #pragma unroll
            for (int rr = 0; rr < 4; ++rr) {
                int row = 16 * w + 4 * kg + rr;
                atomicAdd(&p1n[(size_t)sIdxJ[row] * 32 + 16 * nt + r16], tanhf(ia[rr] + bb));
            }
        }
    }
    __syncthreads();

    // ---- restage pi3 weights into same slots ----
    {
        const int4* g1w = (const int4*)((const char*)wb + OW1T3 * 2);
        const int4* g2w = (const int4*)((const char*)wb + OW2T3 * 2);
        const int4* giw = (const int4*)((const char*)wb + OII3T * 2);
        for (int i = tid; i < 288; i += 256) ((int4*)sW1t)[i] = g1w[i];
        for (int i = tid; i < 160; i += 256) ((int4*)sW2t)[i] = g2w[i];
        for (int i = tid; i < 160; i += 256) ((int4*)sIIt)[i] = giw[i];
    }
    __syncthreads();

    u16* sG2 = sH2;   // [64][40] overlay (h2 dead)
    const int4* gBl3 = (const int4*)((const char*)wb + OBL3G * 2);

    for (int d = 0; d < 3; ++d) {
        // gather inter3
        for (int i = tid; i < 512; i += 256) {
            int e = i >> 3, hf = (i >> 2) & 1, q = i & 3;
            int node = hf ? sIdxJ[e] : sIdxI[e];
            *(int4*)(sA + e * 72 + hf * 32 + q * 8) =
                *(const int4*)(p3hb + ((size_t)(node * 3 + d)) * 32 + q * 8);
        }
        __syncthreads();
        // g1 = inter3@W1p3 + b
        {
            f4v ga0 = {0.f, 0.f, 0.f, 0.f}, ga1 = {0.f, 0.f, 0.f, 0.f};
            #pragma unroll
            for (int ks = 0; ks < 2; ++ks) {
                s8v av = *(const s8v*)(sA + (16 * w + r16) * 72 + 32 * ks + 8 * kg);
                s8v b0 = *(const s8v*)(sW1t + (r16) * 72 + 32 * ks + 8 * kg);
                s8v b1f = *(const s8v*)(sW1t + (16 + r16) * 72 + 32 * ks + 8 * kg);
                ga0 = __builtin_amdgcn_mfma_f32_16x16x32_bf16(av, b0, ga0, 0, 0, 0);
                ga1 = __builtin_amdgcn_mfma_f32_16x16x32_bf16(av, b1f, ga1, 0, 0, 0);
            }
            float bb0 = b13[r16], bb1 = b13[16 + r16];
            #pragma unroll
            for (int rr = 0; rr < 4; ++rr) {
                sBufA[(16 * w + 4 * kg + rr) * 40 + r16]      = (u16)f2b(ga0[rr] + bb0);
                sBufA[(16 * w + 4 * kg + rr) * 40 + 16 + r16] = (u16)f2b(ga1[rr] + bb1);
            }
        }
        __syncthreads();
        // g2 = g1@W2p3 + b  ([32][40] weights)
        {
            s8v av = *(const s8v*)(sBufA + (16 * w + r16) * 40 + 8 * kg);
            #pragma unroll
            for (int nt = 0; nt < 2; ++nt) {
                f4v ga = {0.f, 0.f, 0.f, 0.f};
                s8v bv = *(const s8v*)(sW2t + (16 * nt + r16) * 40 + 8 * kg);
                ga = __builtin_amdgcn_mfma_f32_16x16x32_bf16(av, bv, ga, 0, 0, 0);
                float bb = b23[16 * nt + r16];
                #pragma unroll
                for (int rr = 0; rr < 4; ++rr)
                    sG2[(16 * w + 4 * kg + rr) * 40 + 16 * nt + r16] = (u16)f2b(ga[rr] + bb);
            }
        }
        __syncthreads();
        // W3-pi3 (u-form): K=256 in 2 chunks
        f4v pa0 = {0.f, 0.f, 0.f, 0.f}, pa1 = {0.f, 0.f, 0.f, 0.f};
        for (int c2 = 0; c2 < 2; ++c2) {
            for (int i = tid; i < 544; i += 256) ((int4*)sA)[i] = gBl3[c2 * 544 + i];
            __syncthreads();
            #pragma unroll
            for (int t = 0; t < 4; ++t) {
                float gv = b2f(sG2[(16 * w + r16) * 40 + 16 * c2 + 4 * t + kg]);
                s8v av;
                #pragma unroll
                for (int j = 0; j < 8; ++j) av[j] = f2b(gv * bs[j]);
                s8v b0 = *(const s8v*)(sA + (r16) * 136 + 32 * t + 8 * kg);
                s8v b1f = *(const s8v*)(sA + (16 + r16) * 136 + 32 * t + 8 * kg);
                pa0 = __builtin_amdgcn_mfma_f32_16x16x32_bf16(av, b0, pa0, 0, 0, 0);
                pa1 = __builtin_amdgcn_mfma_f32_16x16x32_bf16(av, b1f, pa1, 0, 0, 0);
            }
            __syncthreads();
        }
        // i3pre -> bufA bf16
        #pragma unroll
        for (int rr = 0; rr < 4; ++rr) {
            sBufA[(16 * w + 4 * kg + rr) * 40 + r16]      = (u16)f2b(pa0[rr]);
            sBufA[(16 * w + 4 * kg + rr) * 40 + 16 + r16] = (u16)f2b(pa1[rr]);
        }
        __syncthreads();
        // ii3 + combine + atomic p3n
        {
            s8v av = *(const s8v*)(sBufA + (16 * w + r16) * 40 + 8 * kg);
            #pragma unroll
            for (int nt = 0; nt < 2; ++nt) {
                f4v ja = {0.f, 0.f, 0.f, 0.f};
                s8v bv = *(const s8v*)(sIIt + (16 * nt + r16) * 40 + 8 * kg);
                ja = __builtin_amdgcn_mfma_f32_16x16x32_bf16(av, bv, ja, 0, 0, 0);
                float bb = ii3b[16 * nt + r16];
                #pragma unroll
                for (int rr = 0; rr < 4; ++rr) {
                    int row = 16 * w + 4 * kg + rr;
                    float i3a = tanhf(ja[rr] + bb);
                    float v12 = nt ? i12b[rr] : i12a[rr];
                    float v13 = nt ? i13b[rr] : i13a[rr];
                    float val = i3a * v12 + sR3[row * 4 + d] * v13;
                    atomicAdd(&p3n[((size_t)sIdxJ[row] * 3 + d) * 32 + 16 * nt + r16], val);
                }
            }
        }
        __syncthreads();
    }
}

// ---------------- finalize: p1o = sum_d p3n^2 + p1n ; p3o = p3n * p1o -----
__global__ __launch_bounds__(256) void finalize_kernel(
    const float* __restrict__ p1n, const float* __restrict__ p3n,
    float* __restrict__ out)
{
    int t = blockIdx.x * 256 + threadIdx.x;   // < NN*32
    int n = t >> 5, c = t & 31;
    float a0 = p3n[(n * 3 + 0) * 32 + c];
    float a1 = p3n[(n * 3 + 1) * 32 + c];
    float a2 = p3n[(n * 3 + 2) * 32 + c];
    float p1o = p1n[t] + a0 * a0 + a1 * a1 + a2 * a2;
    out[t] = p1o;
    float* o3 = out + NN * 32;
    o3[(n * 3 + 0) * 32 + c] = a0 * p1o;
    o3[(n * 3 + 1) * 32 + c] = a1 * p1o;
    o3[(n * 3 + 2) * 32 + c] = a2 * p1o;
}

extern "C" void kernel_launch(void* const* d_in, const int* in_sizes, int n_in,
                              void* d_out, int out_size, void* d_ws, size_t ws_size,
                              hipStream_t stream) {
    const float* p1     = (const float*)d_in[0];
    const float* p3     = (const float*)d_in[1];
    const float* r3     = (const float*)d_in[2];
    const float* basis  = (const float*)d_in[3];
    const int*   idx_i  = (const int*)d_in[4];
    const int*   idx_j  = (const int*)d_in[5];
    const float* pp1_W  = (const float*)d_in[6];
    const float* pp1_b  = (const float*)d_in[7];
    const float* pi1_W1 = (const float*)d_in[8];
    const float* pi1_b1 = (const float*)d_in[9];
    const float* pi1_W2 = (const float*)d_in[10];
    const float* pi1_b2 = (const float*)d_in[11];
    const float* pi1_W3 = (const float*)d_in[12];
    const float* ii1_W  = (const float*)d_in[13];
    const float* ii1_b  = (const float*)d_in[14];
    const float* pp3_W  = (const float*)d_in[15];
    const float* pp3_b  = (const float*)d_in[16];
    const float* pi3_W1 = (const float*)d_in[17];
    const float* pi3_b1 = (const float*)d_in[18];
    const float* pi3_W2 = (const float*)d_in[19];
    const float* pi3_b2 = (const float*)d_in[20];
    const float* pi3_W3 = (const float*)d_in[21];
    const float* ii3_W  = (const float*)d_in[22];
    const float* ii3_b  = (const float*)d_in[23];

    char* ws = (char*)d_ws;
    u16*   p1hb = (u16*)(ws + OFF_P1HB);
    u16*   p3hb = (u16*)(ws + OFF_P3HB);
    float* p1n  = (float*)(ws + OFF_P1N);
    float* p3n  = (float*)(ws + OFF_P3N);
    u16*   wb   = (u16*)(ws + OFF_WB);

    hipMemsetAsync(p1n, 0, 5120000, stream);

    node_prep<<<dim3(5000), dim3(256), 0, stream>>>(p1, p3, pp1_W, pp1_b, pp3_W, pp3_b, p1hb, p3hb);

    wprep<<<dim3((NWB + 255) / 256), dim3(256), 0, stream>>>(
        pi1_W1, pi1_W2, pi1_W3, ii1_W, pi3_W1, pi3_W2, pi3_W3, ii3_W, wb);

    edge_kernel<<<dim3(NE / TE), dim3(256), 0, stream>>>(
        p1hb, p3hb, r3, basis, idx_i, idx_j, wb,
        pi1_b1, pi1_b2, ii1_b, pi3_b1, pi3_b2, ii3_b,
        p1n, p3n);

    finalize_kernel<<<dim3(1250), dim3(256), 0, stream>>>(p1n, p3n, (float*)d_out);
}

// Round 3
// 221.349 us; speedup vs baseline: 5.1344x; 1.0889x over previous
//
#include <hip/hip_runtime.h>
#include <math.h>

#define NN 10000
#define NE 160000
#define TE 64

typedef __attribute__((ext_vector_type(8))) short s8v;
typedef __attribute__((ext_vector_type(4))) float f4v;
typedef unsigned short u16;

// ---- ws byte layout ----
#define OFF_P1HB 0u          // N*32 bf16      = 640000 B
#define OFF_P3HB 640000u     // N*3*32 bf16    = 1920000 B
#define OFF_P1N  2560000u    // N*32 f32       = 1280000 B
#define OFF_P3N  3840000u    // N*3*32 f32     = 3840000 B
#define OFF_WB   7680000u    // bf16 weights

// ---- wb (ushort element) offsets ----
#define OW1T1 0       // [32 c][72 kpad]  (k<64)
#define OW2T1 2304    // [96 c][40 kpad]  (k<32)
#define OII1T 6144    // [32 c][40 kpad]
#define OW1T3 7424    // [32 c][72 kpad]
#define OW2T3 9728    // [32 c][40 kpad]
#define OII3T 11008   // [32 c][40 kpad]
#define OBLG  12288   // [8 b][96 c][104 kpad]  (k<96)   = 79872
#define OBL3G 92160   // [8 b][32 c][40 kpad]   (k<32)   = 10240
#define NWB   102400

__device__ __forceinline__ short f2b(float f) {
    unsigned u = __float_as_uint(f);
    u += 0x7fffu + ((u >> 16) & 1u);
    return (short)(u >> 16);
}
__device__ __forceinline__ float tanhf_fast(float x) {
    float xc = fminf(9.f, fmaxf(-9.f, x));
    float e = __expf(2.f * xc);
    return (e - 1.f) * __builtin_amdgcn_rcpf(e + 1.f);
}

// ---------------- node prep: p1h/p3h = tanh(x@W+b) -> bf16 ----------------
__global__ __launch_bounds__(256) void node_prep(
    const float* __restrict__ p1, const float* __restrict__ p3,
    const float* __restrict__ pp1_W, const float* __restrict__ pp1_b,
    const float* __restrict__ pp3_W, const float* __restrict__ pp3_b,
    u16* __restrict__ p1hb, u16* __restrict__ p3hb)
{
    __shared__ float Ws[2][32 * 32];
    __shared__ float bsm[2][32];
    int tid = threadIdx.x;
    for (int i = tid; i < 32 * 32; i += 256) { Ws[0][i] = pp1_W[i]; Ws[1][i] = pp3_W[i]; }
    if (tid < 32) { bsm[0][tid] = pp1_b[tid]; bsm[1][tid] = pp3_b[tid]; }
    __syncthreads();
    int idx = blockIdx.x * 256 + tid;      // < NN*128
    int n = idx >> 7;
    int r = (idx >> 5) & 3;
    int c = idx & 31;
    int sel = (r == 0) ? 0 : 1;
    const float* in = (r == 0) ? (p1 + n * 32) : (p3 + (n * 3 + (r - 1)) * 32);
    float acc = bsm[sel][c];
    #pragma unroll
    for (int k = 0; k < 32; ++k) acc += in[k] * Ws[sel][k * 32 + c];
    short v = f2b(tanhf(acc));
    if (r == 0) p1hb[n * 32 + c] = (u16)v;
    else        p3hb[(n * 3 + (r - 1)) * 32 + c] = (u16)v;
}

// ---------------- weight prep: transpose/convert to bf16 with pads --------
__global__ __launch_bounds__(256) void wprep(
    const float* __restrict__ W1, const float* __restrict__ W2,
    const float* __restrict__ W3, const float* __restrict__ ii1,
    const float* __restrict__ W13, const float* __restrict__ W23,
    const float* __restrict__ W33, const float* __restrict__ ii3,
    u16* __restrict__ wb)
{
    int i0 = blockIdx.x * 256 + threadIdx.x;
    if (i0 >= NWB) return;
    int i = i0;
    float v = 0.f;
    if (i < 2304) { int c = i / 72, k = i % 72; if (k < 64) v = W1[k * 32 + c]; }
    else if ((i -= 2304) < 3840) { int c = i / 40, k = i % 40; if (k < 32) v = W2[k * 96 + c]; }
    else if ((i -= 3840) < 1280) { int c = i / 40, k = i % 40; if (k < 32) v = ii1[k * 32 + c]; }
    else if ((i -= 1280) < 2304) { int c = i / 72, k = i % 72; if (k < 64) v = W13[k * 32 + c]; }
    else if ((i -= 2304) < 1280) { int c = i / 40, k = i % 40; if (k < 32) v = W23[k * 32 + c]; }
    else if ((i -= 1280) < 1280) { int c = i / 40, k = i % 40; if (k < 32) v = ii3[k * 32 + c]; }
    else if ((i -= 1280) < 79872) {
        int b = i / 9984, r = i % 9984, c = r / 104, k = r % 104;
        if (k < 96) v = W3[k * 768 + c * 8 + b];
    } else {
        i -= 79872;
        int b = i / 1280, r = i % 1280, c = r / 40, k = r % 40;
        if (k < 32) v = W33[k * 256 + c * 8 + b];
    }
    wb[i0] = (u16)f2b(v);
}

// ------- fused edge kernel: TE=64 edges, 4 waves, wave-autonomous ---------
__global__ __launch_bounds__(256) void edge_kernel(
    const u16* __restrict__ p1hb, const u16* __restrict__ p3hb,
    const float* __restrict__ r3, const float* __restrict__ basis,
    const int* __restrict__ idx_i, const int* __restrict__ idx_j,
    const u16* __restrict__ wb,
    const float* __restrict__ b1, const float* __restrict__ b2,
    const float* __restrict__ ii1b,
    const float* __restrict__ b13, const float* __restrict__ b23,
    const float* __restrict__ ii3b,
    float* __restrict__ p1n, float* __restrict__ p3n)
{
    // LDS 31232 B: all arrays are per-wave row-sliced (rows 16w..16w+15)
    __shared__ int4 smem4[31232 / 16];
    char* sm = (char*)smem4;
    int*   sIdxI  = (int*)(sm + 0);        // [64]
    int*   sIdxJ  = (int*)(sm + 256);      // [64]
    float* sBas   = (float*)(sm + 512);    // [64][8]
    float* sR3    = (float*)(sm + 2560);   // [64][4]
    u16*   sInter = (u16*)(sm + 3584);     // [64][72]
    u16*   sH2    = (u16*)(sm + 12800);    // [64][104]; later g2 overlay [64][40]
    u16*   sBufA  = (u16*)(sm + 26112);    // [64][40]

    const int tid = threadIdx.x;
    const int w   = tid >> 6;
    const int l   = tid & 63;
    const int r16 = l & 15;
    const int kg  = l >> 4;
    const int eb  = blockIdx.x * TE;
    const int rowA = 16 * w + r16;

    // ---- per-wave staging of meta ----
    if (l < 16)       sIdxI[16 * w + l] = idx_i[eb + 16 * w + l];
    else if (l < 32)  sIdxJ[16 * w + (l - 16)] = idx_j[eb + 16 * w + (l - 16)];
    else if (l < 48) {
        int e = 16 * w + (l - 32);
        sR3[e * 4 + 0] = r3[(eb + e) * 3 + 0];
        sR3[e * 4 + 1] = r3[(eb + e) * 3 + 1];
        sR3[e * 4 + 2] = r3[(eb + e) * 3 + 2];
    }
    if (l < 32) {
        int e = 16 * w + (l >> 1);
        ((float4*)(sBas + e * 8))[l & 1] = ((const float4*)(basis + (size_t)(eb + e) * 8))[l & 1];
    }

    // per-lane persistent regs: basis for this lane's 4 D-rows
    float bsv[4][8];
    #pragma unroll
    for (int rr = 0; rr < 4; ++rr) {
        int row = 16 * w + 4 * kg + rr;
        #pragma unroll
        for (int b = 0; b < 8; ++b) bsv[rr][b] = sBas[row * 8 + b];
    }

    // ---- gather inter1 = [p1h[i] | p1h[j]] -> sInter rows of this wave ----
    #pragma unroll
    for (int j2 = 0; j2 < 2; ++j2) {
        int job = l + 64 * j2;                  // 128 jobs per wave
        int e = 16 * w + (job >> 3), hf = (job >> 2) & 1, q = job & 3;
        int node = hf ? sIdxJ[e] : sIdxI[e];
        *(int4*)(sInter + e * 72 + hf * 32 + q * 8) =
            *(const int4*)(p1hb + (size_t)node * 32 + q * 8);
    }

    // ---- h1 = inter1@W1 + b1 -> sBufA bf16 [64][40] ----
    {
        const u16* gW = wb + OW1T1;
        f4v a0 = {0.f,0.f,0.f,0.f}, a1 = {0.f,0.f,0.f,0.f};
        #pragma unroll
        for (int ks = 0; ks < 2; ++ks) {
            s8v av = *(const s8v*)(sInter + rowA * 72 + 32 * ks + 8 * kg);
            s8v bv0 = *(const s8v*)(gW + (r16) * 72 + 32 * ks + 8 * kg);
            s8v bv1 = *(const s8v*)(gW + (16 + r16) * 72 + 32 * ks + 8 * kg);
            a0 = __builtin_amdgcn_mfma_f32_16x16x32_bf16(av, bv0, a0, 0, 0, 0);
            a1 = __builtin_amdgcn_mfma_f32_16x16x32_bf16(av, bv1, a1, 0, 0, 0);
        }
        float bb0 = b1[r16], bb1 = b1[16 + r16];
        #pragma unroll
        for (int rr = 0; rr < 4; ++rr) {
            int row = 16 * w + 4 * kg + rr;
            sBufA[row * 40 + r16]      = (u16)f2b(a0[rr] + bb0);
            sBufA[row * 40 + 16 + r16] = (u16)f2b(a1[rr] + bb1);
        }
    }

    // ---- h2 = h1@W2 + b2 -> sH2 bf16 [64][104] ----
    {
        const u16* gW = wb + OW2T1;
        s8v av = *(const s8v*)(sBufA + rowA * 40 + 8 * kg);
        #pragma unroll
        for (int nt = 0; nt < 6; ++nt) {
            f4v z = {0.f,0.f,0.f,0.f};
            s8v bv = *(const s8v*)(gW + (16 * nt + r16) * 40 + 8 * kg);
            f4v acc = __builtin_amdgcn_mfma_f32_16x16x32_bf16(av, bv, z, 0, 0, 0);
            float bb = b2[16 * nt + r16];
            #pragma unroll
            for (int rr = 0; rr < 4; ++rr)
                sH2[(16 * w + 4 * kg + rr) * 104 + 16 * nt + r16] = (u16)f2b(acc[rr] + bb);
        }
    }

    // ---- pi1-W3 b-form: accT[e,c] = sum_b basis[e,b] * (h2 @ W3_b)[e,c] ----
    f4v accT[6];
    #pragma unroll
    for (int nt = 0; nt < 6; ++nt) { f4v z = {0.f,0.f,0.f,0.f}; accT[nt] = z; }
    {
        s8v af[3];
        #pragma unroll
        for (int ks = 0; ks < 3; ++ks)
            af[ks] = *(const s8v*)(sH2 + rowA * 104 + 32 * ks + 8 * kg);
        const u16* gBl = wb + OBLG;
        #pragma unroll
        for (int b = 0; b < 8; ++b) {
            f4v Db[6];
            #pragma unroll
            for (int nt = 0; nt < 6; ++nt) { f4v z = {0.f,0.f,0.f,0.f}; Db[nt] = z; }
            const u16* bp = gBl + (size_t)b * 9984 + (size_t)r16 * 104 + 8 * kg;
            #pragma unroll
            for (int nt = 0; nt < 6; ++nt) {
                const u16* bpn = bp + nt * 16 * 104;
                #pragma unroll
                for (int ks = 0; ks < 3; ++ks) {
                    s8v bv = *(const s8v*)(bpn + 32 * ks);
                    Db[nt] = __builtin_amdgcn_mfma_f32_16x16x32_bf16(af[ks], bv, Db[nt], 0, 0, 0);
                }
            }
            #pragma unroll
            for (int nt = 0; nt < 6; ++nt)
                #pragma unroll
                for (int rr = 0; rr < 4; ++rr) accT[nt][rr] += bsv[rr][b] * Db[nt][rr];
        }
    }
    // i1_1 -> sBufA bf16 ; i1_2/i1_3 stay in accT[2..5]
    #pragma unroll
    for (int nt = 0; nt < 2; ++nt)
        #pragma unroll
        for (int rr = 0; rr < 4; ++rr)
            sBufA[(16 * w + 4 * kg + rr) * 40 + 16 * nt + r16] = (u16)f2b(accT[nt][rr]);

    // ---- ii1: tanh(i1_1@ii1_W + b) -> atomic p1n[idx_j] ----
    {
        const u16* gW = wb + OII1T;
        s8v av = *(const s8v*)(sBufA + rowA * 40 + 8 * kg);
        #pragma unroll
        for (int nt = 0; nt < 2; ++nt) {
            f4v z = {0.f,0.f,0.f,0.f};
            s8v bv = *(const s8v*)(gW + (16 * nt + r16) * 40 + 8 * kg);
            f4v ia = __builtin_amdgcn_mfma_f32_16x16x32_bf16(av, bv, z, 0, 0, 0);
            float bb = ii1b[16 * nt + r16];
            #pragma unroll
            for (int rr = 0; rr < 4; ++rr) {
                int row = 16 * w + 4 * kg + rr;
                atomicAdd(&p1n[(size_t)sIdxJ[row] * 32 + 16 * nt + r16],
                          tanhf_fast(ia[rr] + bb));
            }
        }
    }

    // ---- pi3 branch: per Cartesian d ----
    u16* sG2 = sH2;   // overlay [64][40] (h2 consumed into af already)
    const u16* gBl3 = wb + OBL3G;
    for (int d = 0; d < 3; ++d) {
        // gather inter3
        #pragma unroll
        for (int j2 = 0; j2 < 2; ++j2) {
            int job = l + 64 * j2;
            int e = 16 * w + (job >> 3), hf = (job >> 2) & 1, q = job & 3;
            int node = hf ? sIdxJ[e] : sIdxI[e];
            *(int4*)(sInter + e * 72 + hf * 32 + q * 8) =
                *(const int4*)(p3hb + ((size_t)(node * 3 + d)) * 32 + q * 8);
        }
        // g1 = inter3@W1p3 + b
        {
            const u16* gW = wb + OW1T3;
            f4v a0 = {0.f,0.f,0.f,0.f}, a1 = {0.f,0.f,0.f,0.f};
            #pragma unroll
            for (int ks = 0; ks < 2; ++ks) {
                s8v av = *(const s8v*)(sInter + rowA * 72 + 32 * ks + 8 * kg);
                s8v bv0 = *(const s8v*)(gW + (r16) * 72 + 32 * ks + 8 * kg);
                s8v bv1 = *(const s8v*)(gW + (16 + r16) * 72 + 32 * ks + 8 * kg);
                a0 = __builtin_amdgcn_mfma_f32_16x16x32_bf16(av, bv0, a0, 0, 0, 0);
                a1 = __builtin_amdgcn_mfma_f32_16x16x32_bf16(av, bv1, a1, 0, 0, 0);
            }
            float bb0 = b13[r16], bb1 = b13[16 + r16];
            #pragma unroll
            for (int rr = 0; rr < 4; ++rr) {
                int row = 16 * w + 4 * kg + rr;
                sBufA[row * 40 + r16]      = (u16)f2b(a0[rr] + bb0);
                sBufA[row * 40 + 16 + r16] = (u16)f2b(a1[rr] + bb1);
            }
        }
        // g2 = g1@W2p3 + b -> sG2 [64][40]
        {
            const u16* gW = wb + OW2T3;
            s8v av = *(const s8v*)(sBufA + rowA * 40 + 8 * kg);
            #pragma unroll
            for (int nt = 0; nt < 2; ++nt) {
                f4v z = {0.f,0.f,0.f,0.f};
                s8v bv = *(const s8v*)(gW + (16 * nt + r16) * 40 + 8 * kg);
                f4v acc = __builtin_amdgcn_mfma_f32_16x16x32_bf16(av, bv, z, 0, 0, 0);
                float bb = b23[16 * nt + r16];
                #pragma unroll
                for (int rr = 0; rr < 4; ++rr)
                    sG2[(16 * w + 4 * kg + rr) * 40 + 16 * nt + r16] = (u16)f2b(acc[rr] + bb);
            }
        }
        // pi3-W3 b-form: pT[e,c] = sum_b basis[e,b] * (g2 @ W33_b)[e,c]
        f4v pT[2];
        { f4v z = {0.f,0.f,0.f,0.f}; pT[0] = z; pT[1] = z; }
        {
            s8v av = *(const s8v*)(sG2 + rowA * 40 + 8 * kg);
            #pragma unroll
            for (int b = 0; b < 8; ++b) {
                const u16* bp = gBl3 + (size_t)b * 1280 + (size_t)r16 * 40 + 8 * kg;
                f4v z = {0.f,0.f,0.f,0.f};
                s8v bv0 = *(const s8v*)(bp);
                s8v bv1 = *(const s8v*)(bp + 16 * 40);
                f4v D0 = __builtin_amdgcn_mfma_f32_16x16x32_bf16(av, bv0, z, 0, 0, 0);
                f4v D1 = __builtin_amdgcn_mfma_f32_16x16x32_bf16(av, bv1, z, 0, 0, 0);
                #pragma unroll
                for (int rr = 0; rr < 4; ++rr) {
                    pT[0][rr] += bsv[rr][b] * D0[rr];
                    pT[1][rr] += bsv[rr][b] * D1[rr];
                }
            }
        }
        // i3pre -> sBufA bf16
        #pragma unroll
        for (int rr = 0; rr < 4; ++rr) {
            int row = 16 * w + 4 * kg + rr;
            sBufA[row * 40 + r16]      = (u16)f2b(pT[0][rr]);
            sBufA[row * 40 + 16 + r16] = (u16)f2b(pT[1][rr]);
        }
        // ii3 + combine + atomic p3n
        {
            const u16* gW = wb + OII3T;
            s8v av = *(const s8v*)(sBufA + rowA * 40 + 8 * kg);
            #pragma unroll
            for (int nt = 0; nt < 2; ++nt) {
                f4v z = {0.f,0.f,0.f,0.f};
                s8v bv = *(const s8v*)(gW + (16 * nt + r16) * 40 + 8 * kg);
                f4v ja = __builtin_amdgcn_mfma_f32_16x16x32_bf16(av, bv, z, 0, 0, 0);
                float bb = ii3b[16 * nt + r16];
                #pragma unroll
                for (int rr = 0; rr < 4; ++rr) {
                    int row = 16 * w + 4 * kg + rr;
                    float i3a = tanhf_fast(ja[rr] + bb);
                    float val = i3a * accT[2 + nt][rr] + sR3[row * 4 + d] * accT[4 + nt][rr];
                    atomicAdd(&p3n[((size_t)sIdxJ[row] * 3 + d) * 32 + 16 * nt + r16], val);
                }
            }
        }
    }
}

// ---------------- finalize: p1o = sum_d p3n^2 + p1n ; p3o = p3n * p1o -----
__global__ __launch_bounds__(256) void finalize_kernel(
    const float* __restrict__ p1n, const float* __restrict__ p3n,
    float* __restrict__ out)
{
    int t = blockIdx.x * 256 + threadIdx.x;   // < NN*32
    int n = t >> 5, c = t & 31;
    float a0 = p3n[(n * 3 + 0) * 32 + c];
    float a1 = p3n[(n * 3 + 1) * 32 + c];
    float a2 = p3n[(n * 3 + 2) * 32 + c];
    float p1o = p1n[t] + a0 * a0 + a1 * a1 + a2 * a2;
    out[t] = p1o;
    float* o3 = out + NN * 32;
    o3[(n * 3 + 0) * 32 + c] = a0 * p1o;
    o3[(n * 3 + 1) * 32 + c] = a1 * p1o;
    o3[(n * 3 + 2) * 32 + c] = a2 * p1o;
}

extern "C" void kernel_launch(void* const* d_in, const int* in_sizes, int n_in,
                              void* d_out, int out_size, void* d_ws, size_t ws_size,
                              hipStream_t stream) {
    const float* p1     = (const float*)d_in[0];
    const float* p3     = (const float*)d_in[1];
    const float* r3     = (const float*)d_in[2];
    const float* basis  = (const float*)d_in[3];
    const int*   idx_i  = (const int*)d_in[4];
    const int*   idx_j  = (const int*)d_in[5];
    const float* pp1_W  = (const float*)d_in[6];
    const float* pp1_b  = (const float*)d_in[7];
    const float* pi1_W1 = (const float*)d_in[8];
    const float* pi1_b1 = (const float*)d_in[9];
    const float* pi1_W2 = (const float*)d_in[10];
    const float* pi1_b2 = (const float*)d_in[11];
    const float* pi1_W3 = (const float*)d_in[12];
    const float* ii1_W  = (const float*)d_in[13];
    const float* ii1_b  = (const float*)d_in[14];
    const float* pp3_W  = (const float*)d_in[15];
    const float* pp3_b  = (const float*)d_in[16];
    const float* pi3_W1 = (const float*)d_in[17];
    const float* pi3_b1 = (const float*)d_in[18];
    const float* pi3_W2 = (const float*)d_in[19];
    const float* pi3_b2 = (const float*)d_in[20];
    const float* pi3_W3 = (const float*)d_in[21];
    const float* ii3_W  = (const float*)d_in[22];
    const float* ii3_b  = (const float*)d_in[23];

    char* ws = (char*)d_ws;
    u16*   p1hb = (u16*)(ws + OFF_P1HB);
    u16*   p3hb = (u16*)(ws + OFF_P3HB);
    float* p1n  = (float*)(ws + OFF_P1N);
    float* p3n  = (float*)(ws + OFF_P3N);
    u16*   wb   = (u16*)(ws + OFF_WB);

    hipMemsetAsync(p1n, 0, 5120000, stream);

    node_prep<<<dim3(5000), dim3(256), 0, stream>>>(p1, p3, pp1_W, pp1_b, pp3_W, pp3_b, p1hb, p3hb);

    wprep<<<dim3((NWB + 255) / 256), dim3(256), 0, stream>>>(
        pi1_W1, pi1_W2, pi1_W3, ii1_W, pi3_W1, pi3_W2, pi3_W3, ii3_W, wb);

    edge_kernel<<<dim3(NE / TE), dim3(256), 0, stream>>>(
        p1hb, p3hb, r3, basis, idx_i, idx_j, wb,
        pi1_b1, pi1_b2, ii1_b, pi3_b1, pi3_b2, ii3_b,
        p1n, p3n);

    finalize_kernel<<<dim3(1250), dim3(256), 0, stream>>>(p1n, p3n, (float*)d_out);
}